// Round 1
// baseline (270.779 us; speedup 1.0000x reference)
//
#include <hip/hip_runtime.h>

#define NEG_INF_F (-1e30f)
#define MARGIN_F 0.1f

// ---- monotone float<->uint key for atomicMax on floats ----
__device__ __forceinline__ unsigned fkey(float f) {
    unsigned b = __float_as_uint(f);
    return (b & 0x80000000u) ? ~b : (b | 0x80000000u);
}
__device__ __forceinline__ float fdec(unsigned k) {
    unsigned b = (k & 0x80000000u) ? (k ^ 0x80000000u) : ~k;
    return __uint_as_float(b);
}

// ============================================================
// Kernel A: per-row pos/neg bitmasks + (block 0) setup/init
//   posbits[j] bit q = any(targets_row[j] == pidxs[qmap[q]][*])
//   negbits[j] bit q = !any(targets_row[j] == nnegs[qmap[q]][*])
// ============================================================
__global__ __launch_bounds__(256) void masks_kernel(
    const float* __restrict__ inputs_col,
    const int* __restrict__ targets_col,
    const int* __restrict__ targets_row,
    const int* __restrict__ qidxs,
    const int* __restrict__ pidxs,
    const int* __restrict__ nnegs,
    unsigned* __restrict__ posbits,
    unsigned* __restrict__ negbits,
    float* __restrict__ qT,          // [d][32] gathered transposed queries
    unsigned* __restrict__ qkeys,    // [32][2] (pos_max, neg_max) keys
    float* __restrict__ accums,      // [32][8]
    int m, int d, int Q, int P, int Nn, int triplet_len)
{
    __shared__ int pl[32 * 16];
    __shared__ int nl[32 * 32];
    __shared__ int qmap[32];
    const int tid = threadIdx.x;

    if (tid < Q) {
        int t = targets_col[tid * triplet_len];
        int l = 0;
        // first match (argmax of equality bools)
        for (int i = Q - 1; i >= 0; --i) if (qidxs[i] == t) l = i;
        qmap[tid] = l;
    }
    __syncthreads();
    for (int i = tid; i < Q * P; i += blockDim.x) {
        int q = i / P, k = i - q * P;
        pl[q * 16 + k] = pidxs[qmap[q] * P + k];
    }
    for (int i = tid; i < Q * Nn; i += blockDim.x) {
        int q = i / Nn, k = i - q * Nn;
        nl[q * 32 + k] = nnegs[qmap[q] * Nn + k];
    }
    if (blockIdx.x == 0) {
        // gather transposed query matrix qT[dd][q]
        for (int i = tid; i < d * Q; i += blockDim.x) {
            int dd = i >> 5, q = i & 31;     // Q == 32
            qT[i] = inputs_col[(size_t)(q * triplet_len) * d + dd];
        }
        if (tid < 2 * Q) qkeys[tid] = fkey(NEG_INF_F);
        if (tid < 8 * Q) accums[tid] = 0.f;
    }
    __syncthreads();

    const int stride = gridDim.x * blockDim.x;
    for (int j = blockIdx.x * blockDim.x + tid; j < m; j += stride) {
        int t = targets_row[j];
        unsigned pb = 0u, nb = 0u;
        for (int q = 0; q < 32; ++q) {
            bool p = false;
            for (int k = 0; k < P; ++k)  p  = p  || (pl[q * 16 + k] == t);
            bool ng = false;
            for (int k = 0; k < Nn; ++k) ng = ng || (nl[q * 32 + k] == t);
            pb |= ((unsigned)p) << q;
            nb |= ((unsigned)(!ng)) << q;
        }
        posbits[j] = pb;
        negbits[j] = nb;
    }
}

// ============================================================
// Kernel B: sims[q][j] = dot(query q, row j)  (32 x m, K = d)
//   + per-block masked max -> global atomicMax via uint keys
// ============================================================
#define BR  256   // rows per block
#define DKC 32    // K-chunk staged in LDS

__global__ __launch_bounds__(256) void sims_kernel(
    const float* __restrict__ qT,        // [d][32]
    const float* __restrict__ rows,      // [m][d]
    const unsigned* __restrict__ posbits,
    const unsigned* __restrict__ negbits,
    float* __restrict__ sims,            // [32][m]
    unsigned* __restrict__ qkeys,        // [32][2]
    int m, int d)
{
    __shared__ float qv[128][32];        // transposed queries (d <= 128)
    __shared__ float rt[BR][DKC + 1];    // padded: conflict-free
    __shared__ unsigned spk[32], snk[32];
    const int tid = threadIdx.x;

    for (int i = tid; i < d * 32; i += 256) qv[i >> 5][i & 31] = qT[i];
    if (tid < 32) { spk[tid] = fkey(NEG_INF_F); snk[tid] = fkey(NEG_INF_F); }

    const int j0 = blockIdx.x * BR;
    const int q0 = (tid & 7) * 4;        // 8 q-groups of 4
    const int r0 = (tid >> 3) * 8;       // 32 r-groups of 8

    float acc[4][8];
#pragma unroll
    for (int a = 0; a < 4; ++a)
#pragma unroll
        for (int b = 0; b < 8; ++b) acc[a][b] = 0.f;

    for (int kc = 0; kc < d; kc += DKC) {
        __syncthreads();
        const int kk = tid & 31;
        const int jj = tid >> 5;
#pragma unroll
        for (int p = 0; p < BR / 8; ++p) {
            int j = j0 + jj + p * 8;
            rt[jj + p * 8][kk] = (j < m) ? rows[(size_t)j * d + kc + kk] : 0.f;
        }
        __syncthreads();
#pragma unroll
        for (int k = 0; k < DKC; ++k) {
            float4 qf = *(const float4*)&qv[kc + k][q0];
            float rv[8];
#pragma unroll
            for (int r = 0; r < 8; ++r) rv[r] = rt[r0 + r][k];
            const float* qfp = (const float*)&qf;
#pragma unroll
            for (int qi = 0; qi < 4; ++qi) {
                float qq = qfp[qi];
#pragma unroll
                for (int r = 0; r < 8; ++r)
                    acc[qi][r] = fmaf(qq, rv[r], acc[qi][r]);
            }
        }
    }

    // masks for my 8 rows
    unsigned pb[8], nb[8];
#pragma unroll
    for (int r = 0; r < 8; ++r) {
        int j = j0 + r0 + r;
        pb[r] = (j < m) ? posbits[j] : 0u;
        nb[r] = (j < m) ? negbits[j] : 0u;
    }

    // store sims + per-thread masked max
#pragma unroll
    for (int qi = 0; qi < 4; ++qi) {
        const int q = q0 + qi;
        float pmax = NEG_INF_F, nmax = NEG_INF_F;
#pragma unroll
        for (int r = 0; r < 8; ++r) {
            if ((pb[r] >> q) & 1u) pmax = fmaxf(pmax, acc[qi][r]);
            if ((nb[r] >> q) & 1u) nmax = fmaxf(nmax, acc[qi][r]);
        }
        if (j0 + r0 + 7 < m) {
            float4 v0 = make_float4(acc[qi][0], acc[qi][1], acc[qi][2], acc[qi][3]);
            float4 v1 = make_float4(acc[qi][4], acc[qi][5], acc[qi][6], acc[qi][7]);
            *(float4*)&sims[(size_t)q * m + j0 + r0]     = v0;
            *(float4*)&sims[(size_t)q * m + j0 + r0 + 4] = v1;
        } else {
#pragma unroll
            for (int r = 0; r < 8; ++r) {
                int j = j0 + r0 + r;
                if (j < m) sims[(size_t)q * m + j] = acc[qi][r];
            }
        }
        atomicMax(&spk[q], fkey(pmax));
        atomicMax(&snk[q], fkey(nmax));
    }
    __syncthreads();
    if (tid < 32) {
        atomicMax(&qkeys[tid * 2],     spk[tid]);
        atomicMax(&qkeys[tid * 2 + 1], snk[tid]);
    }
}

// ============================================================
// Kernel C: selection + masked sums -> atomicAdd accumulators
//   accums[q][0..4] = pos_sum(1-s), pos_cnt, neg_sum(s), neg_cnt, posmask_cnt
// ============================================================
__global__ __launch_bounds__(256) void select_kernel(
    const float* __restrict__ sims,
    const unsigned* __restrict__ posbits,
    const unsigned* __restrict__ negbits,
    const unsigned* __restrict__ qkeys,
    float* __restrict__ accums,
    int m)
{
    const int q = blockIdx.y;
    const float pos_max = fdec(qkeys[q * 2]);
    const float neg_max = fdec(qkeys[q * 2 + 1]);
    const float posThr = neg_max + MARGIN_F;                 // select pos where s < posThr
    const float negThr = fmaxf(0.4f, pos_max) - MARGIN_F;    // select neg where s > negThr

    const int chunk = (m + gridDim.x - 1) / gridDim.x;
    const int jb = blockIdx.x * chunk;
    const int je = min(m, jb + chunk);

    float ps = 0.f, pc = 0.f, ns = 0.f, nc = 0.f, pmc = 0.f;
    for (int j = jb + threadIdx.x; j < je; j += blockDim.x) {
        float s = sims[(size_t)q * m + j];
        unsigned pm = (posbits[j] >> q) & 1u;
        unsigned nm = (negbits[j] >> q) & 1u;
        pmc += (float)pm;
        if (pm && s < posThr) { ps += 1.f - s; pc += 1.f; }
        if (nm && s > negThr) { ns += s;       nc += 1.f; }
    }
    // wave64 reduce, lane 0 of each wave -> atomicAdd
#pragma unroll
    for (int off = 32; off; off >>= 1) {
        ps  += __shfl_down(ps, off);
        pc  += __shfl_down(pc, off);
        ns  += __shfl_down(ns, off);
        nc  += __shfl_down(nc, off);
        pmc += __shfl_down(pmc, off);
    }
    if ((threadIdx.x & 63) == 0) {
        atomicAdd(&accums[q * 8 + 0], ps);
        atomicAdd(&accums[q * 8 + 1], pc);
        atomicAdd(&accums[q * 8 + 2], ns);
        atomicAdd(&accums[q * 8 + 3], nc);
        atomicAdd(&accums[q * 8 + 4], pmc);
    }
}

// ============================================================
// Kernel D: final loss
// ============================================================
__global__ void finalize_kernel(const float* __restrict__ accums,
                                float* __restrict__ out, int Q)
{
    int q = threadIdx.x;  // 64 threads
    float v = 0.f;
    if (q < Q) {
        float ps  = accums[q * 8 + 0];
        float pc  = accums[q * 8 + 1];
        float ns  = accums[q * 8 + 2];
        float nc  = accums[q * 8 + 3];
        float pmc = accums[q * 8 + 4];
        float pl = (pc > 0.f) ? ps / pc : 0.f;
        float nl = (nc > 0.f) ? ns / nc : 0.f;
        v = (pmc > 0.f) ? (pl + nl) : 0.f;
    }
#pragma unroll
    for (int off = 32; off; off >>= 1) v += __shfl_down(v, off);
    if (q == 0) out[0] = v / (float)Q;
}

// ============================================================
extern "C" void kernel_launch(void* const* d_in, const int* in_sizes, int n_in,
                              void* d_out, int out_size, void* d_ws, size_t ws_size,
                              hipStream_t stream)
{
    const float* inputs_col = (const float*)d_in[0];
    const float* inputs_row = (const float*)d_in[1];
    const int* targets_col  = (const int*)d_in[2];
    const int* targets_row  = (const int*)d_in[3];
    const int* qidxs        = (const int*)d_in[4];
    const int* pidxs        = (const int*)d_in[5];
    const int* nnegs        = (const int*)d_in[6];

    const int n  = in_sizes[2];
    const int m  = in_sizes[3];
    const int Q  = in_sizes[4];            // 32
    const int P  = in_sizes[5] / Q;        // 10
    const int Nn = in_sizes[6] / Q;        // 25
    const int d  = in_sizes[0] / n;        // 128
    const int triplet_len = n / Q;         // 12

    char* ws = (char*)d_ws;
    float* sims = (float*)ws;
    size_t off = (size_t)Q * m * sizeof(float);
    unsigned* posbits = (unsigned*)(ws + off); off += (size_t)m * 4;
    unsigned* negbits = (unsigned*)(ws + off); off += (size_t)m * 4;
    float* qT         = (float*)(ws + off);    off += (size_t)d * Q * 4;
    unsigned* qkeys   = (unsigned*)(ws + off); off += (size_t)Q * 2 * 4;
    float* accums     = (float*)(ws + off);    off += (size_t)Q * 8 * 4;

    masks_kernel<<<256, 256, 0, stream>>>(inputs_col, targets_col, targets_row,
                                          qidxs, pidxs, nnegs,
                                          posbits, negbits, qT, qkeys, accums,
                                          m, d, Q, P, Nn, triplet_len);

    const int nb = (m + BR - 1) / BR;
    sims_kernel<<<nb, 256, 0, stream>>>(qT, inputs_row, posbits, negbits,
                                        sims, qkeys, m, d);

    dim3 gsel(32, Q);
    select_kernel<<<gsel, 256, 0, stream>>>(sims, posbits, negbits, qkeys, accums, m);

    finalize_kernel<<<1, 64, 0, stream>>>((const float*)accums, (float*)d_out, Q);
}

// Round 2
// 162.716 us; speedup vs baseline: 1.6641x; 1.6641x over previous
//
#include <hip/hip_runtime.h>

#define NEG_INF_F (-1e30f)
#define MARGIN_F 0.1f
#define TABN 4096
#define BR 128

// ---- monotone float<->uint key for atomicMax on floats ----
__device__ __forceinline__ unsigned fkey(float f) {
    unsigned b = __float_as_uint(f);
    return (b & 0x80000000u) ? ~b : (b | 0x80000000u);
}
__device__ __forceinline__ float fdec(unsigned k) {
    unsigned b = (k & 0x80000000u) ? (k ^ 0x80000000u) : ~k;
    return __uint_as_float(b);
}

// ============================================================
// Kernel A: setup (1 block). Build id->bitmask tables, gather qT,
// init qkeys/accums. 1120 atomicOr instead of 73M compares.
// ============================================================
__global__ __launch_bounds__(256) void setup_kernel(
    const float* __restrict__ inputs_col,
    const int* __restrict__ targets_col,
    const int* __restrict__ qidxs,
    const int* __restrict__ pidxs,
    const int* __restrict__ nnegs,
    unsigned* __restrict__ ptab,    // [TABN]
    unsigned* __restrict__ ntab,    // [TABN]
    float* __restrict__ qT,         // [d][32]
    unsigned* __restrict__ qkeys,   // [32][2]
    float* __restrict__ accums,     // [32][8]
    int d, int Q, int P, int Nn, int triplet_len)
{
    __shared__ int qmap[32];
    const int tid = threadIdx.x;

    if (tid < Q) {
        int t = targets_col[tid * triplet_len];
        int l = 0;
        for (int i = Q - 1; i >= 0; --i) if (qidxs[i] == t) l = i;  // argmax semantics
        qmap[tid] = l;
    }
    for (int i = tid; i < TABN; i += 256) { ptab[i] = 0u; ntab[i] = 0u; }
    if (tid < 2 * Q) qkeys[tid] = fkey(NEG_INF_F);
    if (tid < 8 * Q) accums[tid] = 0.f;
    __syncthreads();

    for (int i = tid; i < Q * P; i += 256) {
        int q = i / P, k = i - q * P;
        int id = pidxs[qmap[q] * P + k];
        if ((unsigned)id < TABN) atomicOr(&ptab[id], 1u << q);
    }
    for (int i = tid; i < Q * Nn; i += 256) {
        int q = i / Nn, k = i - q * Nn;
        int id = nnegs[qmap[q] * Nn + k];
        if ((unsigned)id < TABN) atomicOr(&ntab[id], 1u << q);
    }
    // gather transposed queries qT[dd][q]
    for (int i = tid; i < d * Q; i += 256) {
        int dd = i >> 5, q = i & 31;    // Q == 32
        qT[i] = inputs_col[(size_t)(q * triplet_len) * d + dd];
    }
}

// ============================================================
// Kernel B: sims[q][j] + mask lookup + per-query masked max.
// BR=128 rows/block, 512 blocks (2/CU). k-major row tile so both
// LDS operands are contiguous float4 (conflict-free reads).
// ============================================================
__global__ __launch_bounds__(256) void sims_kernel(
    const float* __restrict__ qT,        // [128][32]
    const float* __restrict__ rows,      // [m][128]
    const int* __restrict__ targets_row,
    const unsigned* __restrict__ ptab,
    const unsigned* __restrict__ ntab,
    float* __restrict__ sims,            // [32][m]
    unsigned* __restrict__ posbits,
    unsigned* __restrict__ negbits,
    unsigned* __restrict__ qkeys,        // [32][2]
    int m, int d)
{
    __shared__ float qv[128][32];        // [k][q]
    __shared__ float rt[32][132];        // [k][j], pad 132: 16B-aligned cols, spread banks
    __shared__ unsigned pbm[BR], nbm[BR];
    __shared__ unsigned spk[32], snk[32];
    const int tid = threadIdx.x;
    const int j0 = blockIdx.x * BR;

    for (int i = tid; i < 128 * 32; i += 256) qv[i >> 5][i & 31] = qT[i];
    if (tid < 32) { spk[tid] = fkey(NEG_INF_F); snk[tid] = fkey(NEG_INF_F); }
    if (tid < BR) {
        int j = j0 + tid;
        unsigned pb = 0u, nb = 0u;
        if (j < m) {
            int t = targets_row[j];
            if ((unsigned)t < TABN) { pb = ptab[t]; nb = ~ntab[t]; }
            else                    { nb = ~0u; }
        }
        pbm[tid] = pb; nbm[tid] = nb;
        if (j < m) { posbits[j] = pb; negbits[j] = nb; }
    }

    const int qg = tid & 7;     // q block: qg*4 .. +3
    const int rg = tid >> 3;    // row block: rg*4 .. +3  (32 groups * 4 = 128)
    const int jj = tid >> 3;    // staging: row within 32-row slab
    const int kk = tid & 7;     // staging: float4 index within 32-k chunk

    float acc[4][4];
#pragma unroll
    for (int a = 0; a < 4; ++a)
#pragma unroll
        for (int b = 0; b < 4; ++b) acc[a][b] = 0.f;

    for (int kc = 0; kc < 128; kc += 32) {
        __syncthreads();
        // stage rows [j0 .. j0+127] x [kc .. kc+31] transposed into rt[k][j]
#pragma unroll
        for (int p = 0; p < 4; ++p) {
            int j = j0 + jj + 32 * p;
            int jc = (j < m) ? j : (m - 1);
            float4 v = *(const float4*)&rows[(size_t)jc * 128 + kc + 4 * kk];
            rt[4 * kk + 0][jj + 32 * p] = v.x;
            rt[4 * kk + 1][jj + 32 * p] = v.y;
            rt[4 * kk + 2][jj + 32 * p] = v.z;
            rt[4 * kk + 3][jj + 32 * p] = v.w;
        }
        __syncthreads();
#pragma unroll
        for (int k = 0; k < 32; ++k) {
            float4 qf = *(const float4*)&qv[kc + k][qg * 4];
            float4 rf = *(const float4*)&rt[k][rg * 4];
            const float* qp = (const float*)&qf;
            const float* rp = (const float*)&rf;
#pragma unroll
            for (int qi = 0; qi < 4; ++qi)
#pragma unroll
                for (int ri = 0; ri < 4; ++ri)
                    acc[qi][ri] = fmaf(qp[qi], rp[ri], acc[qi][ri]);
        }
    }

    // masks for my 4 rows
    unsigned pb[4], nb[4];
#pragma unroll
    for (int r = 0; r < 4; ++r) { pb[r] = pbm[rg * 4 + r]; nb[r] = nbm[rg * 4 + r]; }

    const bool full = (j0 + BR <= m);
#pragma unroll
    for (int qi = 0; qi < 4; ++qi) {
        const int q = qg * 4 + qi;
        float pmax = NEG_INF_F, nmax = NEG_INF_F;
#pragma unroll
        for (int r = 0; r < 4; ++r) {
            if ((pb[r] >> q) & 1u) pmax = fmaxf(pmax, acc[qi][r]);
            if ((nb[r] >> q) & 1u) nmax = fmaxf(nmax, acc[qi][r]);
        }
        // butterfly over lanes sharing qg (stride 8): lanes 0..7 hold full wave max
#pragma unroll
        for (int off = 32; off >= 8; off >>= 1) {
            pmax = fmaxf(pmax, __shfl_down(pmax, off));
            nmax = fmaxf(nmax, __shfl_down(nmax, off));
        }
        if ((tid & 63) < 8) {
            atomicMax(&spk[q], fkey(pmax));
            atomicMax(&snk[q], fkey(nmax));
        }
        // store sims
        if (full) {
            *(float4*)&sims[(size_t)q * m + j0 + rg * 4] =
                make_float4(acc[qi][0], acc[qi][1], acc[qi][2], acc[qi][3]);
        } else {
#pragma unroll
            for (int r = 0; r < 4; ++r) {
                int j = j0 + rg * 4 + r;
                if (j < m) sims[(size_t)q * m + j] = acc[qi][r];
            }
        }
    }
    __syncthreads();
    if (tid < 32) {
        atomicMax(&qkeys[tid * 2],     spk[tid]);
        atomicMax(&qkeys[tid * 2 + 1], snk[tid]);
    }
}

// ============================================================
// Kernel C: selection + masked sums -> atomicAdd accumulators
// ============================================================
__global__ __launch_bounds__(256) void select_kernel(
    const float* __restrict__ sims,
    const unsigned* __restrict__ posbits,
    const unsigned* __restrict__ negbits,
    const unsigned* __restrict__ qkeys,
    float* __restrict__ accums,
    int m)
{
    const int q = blockIdx.y;
    const float pos_max = fdec(qkeys[q * 2]);
    const float neg_max = fdec(qkeys[q * 2 + 1]);
    const float posThr = neg_max + MARGIN_F;
    const float negThr = fmaxf(0.4f, pos_max) - MARGIN_F;

    const int chunk = (m + gridDim.x - 1) / gridDim.x;
    const int jb = blockIdx.x * chunk;
    const int je = min(m, jb + chunk);

    float ps = 0.f, pc = 0.f, ns = 0.f, nc = 0.f, pmc = 0.f;
    for (int j = jb + threadIdx.x; j < je; j += blockDim.x) {
        float s = sims[(size_t)q * m + j];
        unsigned pm = (posbits[j] >> q) & 1u;
        unsigned nm = (negbits[j] >> q) & 1u;
        pmc += (float)pm;
        if (pm && s < posThr) { ps += 1.f - s; pc += 1.f; }
        if (nm && s > negThr) { ns += s;       nc += 1.f; }
    }
#pragma unroll
    for (int off = 32; off; off >>= 1) {
        ps  += __shfl_down(ps, off);
        pc  += __shfl_down(pc, off);
        ns  += __shfl_down(ns, off);
        nc  += __shfl_down(nc, off);
        pmc += __shfl_down(pmc, off);
    }
    if ((threadIdx.x & 63) == 0) {
        atomicAdd(&accums[q * 8 + 0], ps);
        atomicAdd(&accums[q * 8 + 1], pc);
        atomicAdd(&accums[q * 8 + 2], ns);
        atomicAdd(&accums[q * 8 + 3], nc);
        atomicAdd(&accums[q * 8 + 4], pmc);
    }
}

// ============================================================
// Kernel D: final loss
// ============================================================
__global__ void finalize_kernel(const float* __restrict__ accums,
                                float* __restrict__ out, int Q)
{
    int q = threadIdx.x;  // 64 threads
    float v = 0.f;
    if (q < Q) {
        float ps  = accums[q * 8 + 0];
        float pc  = accums[q * 8 + 1];
        float ns  = accums[q * 8 + 2];
        float nc  = accums[q * 8 + 3];
        float pmc = accums[q * 8 + 4];
        float pl = (pc > 0.f) ? ps / pc : 0.f;
        float nl = (nc > 0.f) ? ns / nc : 0.f;
        v = (pmc > 0.f) ? (pl + nl) : 0.f;
    }
#pragma unroll
    for (int off = 32; off; off >>= 1) v += __shfl_down(v, off);
    if (q == 0) out[0] = v / (float)Q;
}

// ============================================================
extern "C" void kernel_launch(void* const* d_in, const int* in_sizes, int n_in,
                              void* d_out, int out_size, void* d_ws, size_t ws_size,
                              hipStream_t stream)
{
    const float* inputs_col = (const float*)d_in[0];
    const float* inputs_row = (const float*)d_in[1];
    const int* targets_col  = (const int*)d_in[2];
    const int* targets_row  = (const int*)d_in[3];
    const int* qidxs        = (const int*)d_in[4];
    const int* pidxs        = (const int*)d_in[5];
    const int* nnegs        = (const int*)d_in[6];

    const int n  = in_sizes[2];
    const int m  = in_sizes[3];
    const int Q  = in_sizes[4];            // 32
    const int P  = in_sizes[5] / Q;        // 10
    const int Nn = in_sizes[6] / Q;        // 25
    const int d  = in_sizes[0] / n;        // 128
    const int triplet_len = n / Q;         // 12

    char* ws = (char*)d_ws;
    float* sims = (float*)ws;
    size_t off = (size_t)Q * m * sizeof(float);
    unsigned* posbits = (unsigned*)(ws + off); off += (size_t)m * 4;
    unsigned* negbits = (unsigned*)(ws + off); off += (size_t)m * 4;
    unsigned* ptab    = (unsigned*)(ws + off); off += (size_t)TABN * 4;
    unsigned* ntab    = (unsigned*)(ws + off); off += (size_t)TABN * 4;
    float* qT         = (float*)(ws + off);    off += (size_t)d * Q * 4;
    unsigned* qkeys   = (unsigned*)(ws + off); off += (size_t)Q * 2 * 4;
    float* accums     = (float*)(ws + off);    off += (size_t)Q * 8 * 4;

    setup_kernel<<<1, 256, 0, stream>>>(inputs_col, targets_col, qidxs, pidxs, nnegs,
                                        ptab, ntab, qT, qkeys, accums,
                                        d, Q, P, Nn, triplet_len);

    const int nb = (m + BR - 1) / BR;
    sims_kernel<<<nb, 256, 0, stream>>>(qT, inputs_row, targets_row, ptab, ntab,
                                        sims, posbits, negbits, qkeys, m, d);

    dim3 gsel(32, Q);
    select_kernel<<<gsel, 256, 0, stream>>>(sims, posbits, negbits, qkeys, accums, m);

    finalize_kernel<<<1, 64, 0, stream>>>((const float*)accums, (float*)d_out, Q);
}

// Round 4
// 138.299 us; speedup vs baseline: 1.9579x; 1.1766x over previous
//
#include <hip/hip_runtime.h>

#define NEG_INF_F (-1e30f)
#define MARGIN_F 0.1f
#define TABN 4096
#define BR 256     // rows per block
#define NT 512     // threads per block

// ---- monotone float<->uint key for LDS atomicMax on floats ----
__device__ __forceinline__ unsigned fkey(float f) {
    unsigned b = __float_as_uint(f);
    return (b & 0x80000000u) ? ~b : (b | 0x80000000u);
}
__device__ __forceinline__ float fdec(unsigned k) {
    unsigned b = (k & 0x80000000u) ? (k ^ 0x80000000u) : ~k;
    return __uint_as_float(b);
}

// ============================================================
// Kernel A: setup (1 block). id->bitmask tables, gathered qT,
// zero accums + barrier counters.
// ============================================================
__global__ __launch_bounds__(256) void setup_kernel(
    const float* __restrict__ inputs_col,
    const int* __restrict__ targets_col,
    const int* __restrict__ qidxs,
    const int* __restrict__ pidxs,
    const int* __restrict__ nnegs,
    unsigned* __restrict__ ptab,    // [TABN]
    unsigned* __restrict__ ntab,    // [TABN]
    float* __restrict__ qT,         // [d][32]
    float* __restrict__ accums,     // [160]
    unsigned* __restrict__ bar,     // [2]: arrive, done
    int d, int Q, int P, int Nn, int triplet_len)
{
    __shared__ int qmap[32];
    const int tid = threadIdx.x;

    if (tid < Q) {
        int t = targets_col[tid * triplet_len];
        int l = 0;
        for (int i = Q - 1; i >= 0; --i) if (qidxs[i] == t) l = i;  // argmax semantics
        qmap[tid] = l;
    }
    for (int i = tid; i < TABN; i += 256) { ptab[i] = 0u; ntab[i] = 0u; }
    if (tid < 160) accums[tid] = 0.f;
    if (tid < 2) bar[tid] = 0u;
    __syncthreads();

    for (int i = tid; i < Q * P; i += 256) {
        int q = i / P, k = i - q * P;
        int id = pidxs[qmap[q] * P + k];
        if ((unsigned)id < TABN) atomicOr(&ptab[id], 1u << q);
    }
    for (int i = tid; i < Q * Nn; i += 256) {
        int q = i / Nn, k = i - q * Nn;
        int id = nnegs[qmap[q] * Nn + k];
        if ((unsigned)id < TABN) atomicOr(&ntab[id], 1u << q);
    }
    for (int i = tid; i < d * Q; i += 256) {
        int dd = i >> 5, q = i & 31;    // Q == 32
        qT[i] = inputs_col[(size_t)(q * triplet_len) * d + dd];
    }
}

// ============================================================
// Manual grid barrier (all blocks guaranteed resident: grid=256
// = #CUs, capacity >= 1 block/CU, so the CP dispatches every
// block before any must wait).
// ============================================================
__device__ __forceinline__ void gsync(unsigned* cnt, unsigned nblk) {
    __syncthreads();
    if (threadIdx.x == 0) {
        __threadfence();                 // release: wb L2 + inv
        atomicAdd(cnt, 1u);              // device-scope
        while (__hip_atomic_load(cnt, __ATOMIC_RELAXED, __HIP_MEMORY_SCOPE_AGENT) < nblk)
            __builtin_amdgcn_s_sleep(2);
        __threadfence();                 // acquire: invalidate stale L1/L2
    }
    __syncthreads();
}

// ============================================================
// Fused kernel (regular launch, 256 blocks x 512 threads):
//  phase1: dots in registers + block masked maxes -> gmax[64][nb]
//  gsync
//  phase2: thresholds from gmax scan, selection on register acc,
//          block partials -> global atomicAdd accums[160]
//  last-block ticket -> finalize -> out[0]
// ============================================================
__global__ __launch_bounds__(NT, 2) void fused_kernel(
    const float* __restrict__ qT,        // [128][32]
    const float* __restrict__ rows,      // [m][128]
    const int* __restrict__ targets_row,
    const unsigned* __restrict__ ptab,
    const unsigned* __restrict__ ntab,
    float* __restrict__ gmax,            // [64][nb]  row = side*32+q
    float* __restrict__ accums,          // [160] = [32][5]
    unsigned* __restrict__ bar,          // [2]
    float* __restrict__ out,
    int m, int nb)
{
    __shared__ float qv[128][32];        // [k][q]
    __shared__ float rt[32][261];        // [k][j], pad 261 -> 2-way max on writes
    __shared__ unsigned pbm[BR], nbm[BR];
    __shared__ unsigned spk[32], snk[32];
    __shared__ float thr[2][32];         // [0]=pos_max [1]=neg_max
    __shared__ float wpart[8][32][5];
    __shared__ int islast;

    const int tid = threadIdx.x;
    const int bid = blockIdx.x;
    const int j0 = bid * BR;

    // ---- phase 1 ----
    for (int i = tid; i < 128 * 32; i += NT) qv[i >> 5][i & 31] = qT[i];
    if (tid < 32) { spk[tid] = fkey(NEG_INF_F); snk[tid] = fkey(NEG_INF_F); }
    if (tid < BR) {
        int j = j0 + tid;
        unsigned pb = 0u, nbv = 0u;
        if (j < m) {
            int t = targets_row[j];
            if ((unsigned)t < TABN) { pb = ptab[t]; nbv = ~ntab[t]; }
            else                    { nbv = ~0u; }
        }
        pbm[tid] = pb; nbm[tid] = nbv;
    }

    const int qg = tid & 7;      // q group: qg*4 .. +3
    const int rg = tid >> 3;     // row group: rg*4 .. +3  (64 groups * 4 = 256)
    const int kk = tid & 7;      // staging: float4 idx within 32-k chunk
    const int jj = tid >> 3;     // staging: row within 64-row slab

    float acc[4][4];
#pragma unroll
    for (int a = 0; a < 4; ++a)
#pragma unroll
        for (int b = 0; b < 4; ++b) acc[a][b] = 0.f;

    for (int kc = 0; kc < 128; kc += 32) {
        __syncthreads();
#pragma unroll
        for (int p = 0; p < 4; ++p) {
            int j = j0 + jj + 64 * p;
            int jc = (j < m) ? j : (m - 1);
            float4 v = *(const float4*)&rows[(size_t)jc * 128 + kc + 4 * kk];
            rt[4 * kk + 0][jj + 64 * p] = v.x;
            rt[4 * kk + 1][jj + 64 * p] = v.y;
            rt[4 * kk + 2][jj + 64 * p] = v.z;
            rt[4 * kk + 3][jj + 64 * p] = v.w;
        }
        __syncthreads();
#pragma unroll
        for (int k = 0; k < 32; ++k) {
            float4 qf = *(const float4*)&qv[kc + k][qg * 4];
            float4 rf = *(const float4*)&rt[k][rg * 4];
            const float* qp = (const float*)&qf;
            const float* rp = (const float*)&rf;
#pragma unroll
            for (int qi = 0; qi < 4; ++qi)
#pragma unroll
                for (int ri = 0; ri < 4; ++ri)
                    acc[qi][ri] = fmaf(qp[qi], rp[ri], acc[qi][ri]);
        }
    }

    unsigned pb[4], nbr[4];
#pragma unroll
    for (int r = 0; r < 4; ++r) { pb[r] = pbm[rg * 4 + r]; nbr[r] = nbm[rg * 4 + r]; }

    // block masked maxes
#pragma unroll
    for (int qi = 0; qi < 4; ++qi) {
        const int q = qg * 4 + qi;
        float pmax = NEG_INF_F, nmax = NEG_INF_F;
#pragma unroll
        for (int r = 0; r < 4; ++r) {
            if ((pb[r] >> q) & 1u)  pmax = fmaxf(pmax, acc[qi][r]);
            if ((nbr[r] >> q) & 1u) nmax = fmaxf(nmax, acc[qi][r]);
        }
#pragma unroll
        for (int off = 32; off >= 8; off >>= 1) {
            pmax = fmaxf(pmax, __shfl_down(pmax, off));
            nmax = fmaxf(nmax, __shfl_down(nmax, off));
        }
        if ((tid & 63) < 8) {
            atomicMax(&spk[q], fkey(pmax));
            atomicMax(&snk[q], fkey(nmax));
        }
    }
    __syncthreads();
    if (tid < 64) {
        int side = tid >> 5, q = tid & 31;
        gmax[(size_t)tid * nb + bid] = fdec(side ? snk[q] : spk[q]);
    }

    gsync(&bar[0], (unsigned)nb);

    // ---- phase 2: thresholds ----
    {
        int p = tid >> 3, c = tid & 7;   // 64 pairs x 8 scanners
        float mv = NEG_INF_F;
        for (int b = c; b < nb; b += 8) mv = fmaxf(mv, gmax[(size_t)p * nb + b]);
#pragma unroll
        for (int msk = 1; msk <= 4; msk <<= 1) mv = fmaxf(mv, __shfl_xor(mv, msk));
        if (c == 0) thr[p >> 5][p & 31] = mv;
    }
    __syncthreads();

    // selection on register acc
    const int wave = tid >> 6, lane = tid & 63;
#pragma unroll
    for (int qi = 0; qi < 4; ++qi) {
        const int q = qg * 4 + qi;
        const float posThr = thr[1][q] + MARGIN_F;               // s < neg_max + margin
        const float negThr = fmaxf(0.4f, thr[0][q]) - MARGIN_F;  // s > max(0.4,pos_max) - margin
        float ps = 0.f, pc = 0.f, ns = 0.f, nc = 0.f, pmc = 0.f;
#pragma unroll
        for (int r = 0; r < 4; ++r) {
            float s = acc[qi][r];
            unsigned pm = (pb[r] >> q) & 1u;
            unsigned nm = (nbr[r] >> q) & 1u;
            pmc += (float)pm;
            if (pm && s < posThr) { ps += 1.f - s; pc += 1.f; }
            if (nm && s > negThr) { ns += s;       nc += 1.f; }
        }
#pragma unroll
        for (int off = 32; off >= 8; off >>= 1) {
            ps  += __shfl_down(ps, off);
            pc  += __shfl_down(pc, off);
            ns  += __shfl_down(ns, off);
            nc  += __shfl_down(nc, off);
            pmc += __shfl_down(pmc, off);
        }
        if (lane < 8) {
            wpart[wave][lane * 4 + qi][0] = ps;
            wpart[wave][lane * 4 + qi][1] = pc;
            wpart[wave][lane * 4 + qi][2] = ns;
            wpart[wave][lane * 4 + qi][3] = nc;
            wpart[wave][lane * 4 + qi][4] = pmc;
        }
    }
    __syncthreads();
    if (tid < 160) {
        float v = 0.f;
#pragma unroll
        for (int w = 0; w < 8; ++w) v += wpart[w][tid / 5][tid % 5];
        atomicAdd(&accums[tid], v);
    }

    // ---- last-block finalize ----
    __syncthreads();                      // all waves drain their atomics at the barrier
    if (tid == 0) {
        __threadfence();
        unsigned old = atomicAdd(&bar[1], 1u);
        islast = (old == (unsigned)(nb - 1)) ? 1 : 0;
    }
    __syncthreads();
    if (islast) {
        if (tid == 0) __threadfence();    // acquire: see all blocks' adds
        __syncthreads();
        if (tid < 64) {
            float v = 0.f;
            if (tid < 32) {
                float psv = accums[tid * 5 + 0];
                float pcv = accums[tid * 5 + 1];
                float nsv = accums[tid * 5 + 2];
                float ncv = accums[tid * 5 + 3];
                float pmc = accums[tid * 5 + 4];
                float pl = (pcv > 0.f) ? psv / pcv : 0.f;
                float nl = (ncv > 0.f) ? nsv / ncv : 0.f;
                v = (pmc > 0.f) ? (pl + nl) : 0.f;
            }
#pragma unroll
            for (int off = 32; off; off >>= 1) v += __shfl_down(v, off);
            if (tid == 0) out[0] = v / 32.0f;
        }
    }
}

// ============================================================
extern "C" void kernel_launch(void* const* d_in, const int* in_sizes, int n_in,
                              void* d_out, int out_size, void* d_ws, size_t ws_size,
                              hipStream_t stream)
{
    const float* inputs_col = (const float*)d_in[0];
    const float* inputs_row = (const float*)d_in[1];
    const int* targets_col  = (const int*)d_in[2];
    const int* targets_row  = (const int*)d_in[3];
    const int* qidxs        = (const int*)d_in[4];
    const int* pidxs        = (const int*)d_in[5];
    const int* nnegs        = (const int*)d_in[6];

    const int n  = in_sizes[2];
    int m        = in_sizes[3];
    const int Q  = in_sizes[4];            // 32
    const int P  = in_sizes[5] / Q;        // 10
    const int Nn = in_sizes[6] / Q;        // 25
    const int d  = in_sizes[0] / n;        // 128
    const int triplet_len = n / Q;         // 12

    int nb = (m + BR - 1) / BR;            // 256

    char* ws = (char*)d_ws;
    size_t off = 0;
    unsigned* ptab = (unsigned*)(ws + off); off += (size_t)TABN * 4;
    unsigned* ntab = (unsigned*)(ws + off); off += (size_t)TABN * 4;
    float* qT      = (float*)(ws + off);    off += (size_t)d * Q * 4;
    float* gmax    = (float*)(ws + off);    off += (size_t)64 * nb * 4;
    float* accums  = (float*)(ws + off);    off += (size_t)160 * 4;
    unsigned* bar  = (unsigned*)(ws + off); off += 2 * 4;
    float* out     = (float*)d_out;

    setup_kernel<<<1, 256, 0, stream>>>(inputs_col, targets_col, qidxs, pidxs, nnegs,
                                        ptab, ntab, qT, accums, bar,
                                        d, Q, P, Nn, triplet_len);

    fused_kernel<<<nb, NT, 0, stream>>>(qT, inputs_row, targets_row, ptab, ntab,
                                        gmax, accums, bar, out, m, nb);
}